// Round 1
// baseline (192.477 us; speedup 1.0000x reference)
//
#include <hip/hip_runtime.h>

#define NN 2048     // nodes per graph
#define NG 64       // graphs
#define NE 16384    // edges per graph
#define BB 65536    // batch
#define META 64
#define TXD 8
#define NOISE 128

// ---------------------------------------------------------------------------
// Kernel 1: per-graph GCN embedding + fold into emb_W -> graph_out [64][128]
// One block per graph. deg/agg live in LDS; deg is a sum of 1.0s (exact).
// ---------------------------------------------------------------------------
__global__ __launch_bounds__(256) void gcn_kernel(
    const int* __restrict__ edges,     // [64,2,16384]
    const float* __restrict__ gcn_w,   // scalar
    const float* __restrict__ gcn_b,   // scalar
    const float* __restrict__ emb_W,   // [2089,128]
    float* __restrict__ graph_out)     // [64,128] (ws)
{
    __shared__ float s_deg[NN];   // deg -> dinv
    __shared__ float s_agg[NN];   // agg -> emb
    __shared__ float s_part[NOISE];

    const int g = blockIdx.x;
    const int tid = threadIdx.x;
    const int* __restrict__ src = edges + (size_t)g * 2 * NE;
    const int* __restrict__ dst = src + NE;

    for (int n = tid; n < NN; n += 256) { s_deg[n] = 1.0f; s_agg[n] = 0.0f; }
    __syncthreads();
    for (int e = tid; e < NE; e += 256) atomicAdd(&s_deg[dst[e]], 1.0f);
    __syncthreads();
    for (int n = tid; n < NN; n += 256) s_deg[n] = rsqrtf(s_deg[n]);
    __syncthreads();
    for (int e = tid; e < NE; e += 256) {
        int s = src[e], d = dst[e];
        atomicAdd(&s_agg[d], s_deg[s] * s_deg[d]);
    }
    __syncthreads();
    const float w = gcn_w[0], b = gcn_b[0];
    for (int n = tid; n < NN; n += 256) {
        float di = s_deg[n];
        s_agg[n] = (s_agg[n] + di * di) * w + b;   // emb[n]
    }
    __syncthreads();

    // graph_out[g][c] = sum_n emb[n] * emb_W[n*128 + c]; split nodes in halves
    const int c = tid & 127, h = tid >> 7;
    const float* __restrict__ Wp = emb_W + (size_t)(h * 1024) * NOISE + c;
    const float* __restrict__ ep = s_agg + h * 1024;
    float a0 = 0.f, a1 = 0.f, a2 = 0.f, a3 = 0.f;
    for (int n = 0; n < 1024; n += 4) {
        a0 = fmaf(ep[n + 0], Wp[(size_t)(n + 0) * NOISE], a0);
        a1 = fmaf(ep[n + 1], Wp[(size_t)(n + 1) * NOISE], a1);
        a2 = fmaf(ep[n + 2], Wp[(size_t)(n + 2) * NOISE], a2);
        a3 = fmaf(ep[n + 3], Wp[(size_t)(n + 3) * NOISE], a3);
    }
    float acc = (a0 + a1) + (a2 + a3);
    if (h == 1) s_part[c] = acc;
    __syncthreads();
    if (h == 0) graph_out[g * NOISE + c] = acc + s_part[c];
}

// ---------------------------------------------------------------------------
// Kernel 2: main batched kernel. 64 rows per block, 8-row chunks.
// Per-thread output-column weights live in registers; trig_W in LDS.
// ---------------------------------------------------------------------------
#define ROWS 64
__global__ __launch_bounds__(256) void main_kernel(
    const int* __restrict__ bg,          // [B]
    const float* __restrict__ chain,     // [B]
    const float* __restrict__ trig_in,   // [B,64]
    const float* __restrict__ txs,       // [B,8]
    const float* __restrict__ trig_W,    // [64,32]
    const float* __restrict__ trig_b,    // [32]
    const float* __restrict__ emb_W,     // [2089,128]
    const float* __restrict__ emb_b,     // [128]
    const float* __restrict__ graph_out, // [64,128]
    float* __restrict__ out)             // [B,128]
{
    __shared__ float s_tw[META * 32];   // trig_W, natural [i][j] layout (8 KB)
    __shared__ float s_tb[32];
    __shared__ float s_td[8 * META];    // 8 staged trigger rows (2 KB)
    __shared__ float s_trig[8 * 32];    // relu'd trig for 8 rows (1 KB)
    __shared__ float s_tx[8 * TXD];
    __shared__ float s_chain[8];
    __shared__ int   s_g[8];

    const int tid = threadIdx.x;
    for (int k = tid; k < META * 32; k += 256) s_tw[k] = trig_W[k];
    if (tid < 32) s_tb[tid] = trig_b[tid];

    // per-thread register weights for output column n
    const int n = tid & 127;
    float w2[32], w3[TXD];
    #pragma unroll
    for (int j = 0; j < 32; ++j) w2[j] = emb_W[(size_t)(2049 + j) * NOISE + n];
    #pragma unroll
    for (int k = 0; k < TXD; ++k) w3[k] = emb_W[(size_t)(2081 + k) * NOISE + n];
    const float w1 = emb_W[(size_t)2048 * NOISE + n];
    const float bias = emb_b[n];

    const int block_row0 = blockIdx.x * ROWS;
    for (int chunk = 0; chunk < ROWS / 8; ++chunk) {
        const int row0 = block_row0 + chunk * 8;
        __syncthreads();   // previous chunk's consumers done before restaging
        if (tid < 128) {
            ((float4*)s_td)[tid] =
                ((const float4*)(trig_in + (size_t)row0 * META))[tid];
        } else if (tid < 144) {
            int t = tid - 128;
            ((float4*)s_tx)[t] = ((const float4*)(txs + (size_t)row0 * TXD))[t];
        } else if (tid < 152) {
            int r = tid - 144;
            s_chain[r] = chain[row0 + r];
        } else if (tid < 160) {
            int r = tid - 152;
            s_g[r] = bg[row0 + r];
        }
        __syncthreads();

        // phase 1: trig[r][j] for 8 rows — one dot(64) per thread
        {
            const int r = tid >> 5, j = tid & 31;
            const float* __restrict__ td = s_td + r * META;
            float acc = s_tb[j];
            #pragma unroll
            for (int i = 0; i < META; ++i)
                acc = fmaf(td[i], s_tw[i * 32 + j], acc);
            s_trig[r * 32 + j] = fmaxf(acc, 0.f);
        }
        __syncthreads();

        // phase 2: 2 rows per pass (tid>>7 selects row), n = tid&127
        #pragma unroll
        for (int rr = 0; rr < 4; ++rr) {
            const int r = rr * 2 + (tid >> 7);
            const int row = row0 + r;
            const int g = s_g[r];
            float acc = bias + graph_out[g * NOISE + n] + s_chain[r] * w1;
            #pragma unroll
            for (int k = 0; k < TXD; ++k)
                acc = fmaf(s_tx[r * TXD + k], w3[k], acc);
            const float* __restrict__ tg = s_trig + r * 32;
            #pragma unroll
            for (int j = 0; j < 32; ++j)
                acc = fmaf(tg[j], w2[j], acc);
            out[(size_t)row * NOISE + n] = acc;
        }
    }
}

extern "C" void kernel_launch(void* const* d_in, const int* in_sizes, int n_in,
                              void* d_out, int out_size, void* d_ws, size_t ws_size,
                              hipStream_t stream) {
    const int*   bg      = (const int*)d_in[0];
    const float* chain   = (const float*)d_in[1];
    const float* trig_in = (const float*)d_in[2];
    const float* txs     = (const float*)d_in[3];
    const int*   edges   = (const int*)d_in[4];
    const float* gcn_w   = (const float*)d_in[5];
    const float* gcn_b   = (const float*)d_in[6];
    const float* trig_W  = (const float*)d_in[7];
    const float* trig_b  = (const float*)d_in[8];
    const float* emb_W   = (const float*)d_in[9];
    const float* emb_b   = (const float*)d_in[10];
    float* out = (float*)d_out;
    float* graph_out = (float*)d_ws;   // 64*128 floats = 32 KB

    gcn_kernel<<<NG, 256, 0, stream>>>(edges, gcn_w, gcn_b, emb_W, graph_out);
    main_kernel<<<BB / ROWS, 256, 0, stream>>>(bg, chain, trig_in, txs, trig_W,
                                               trig_b, emb_W, emb_b, graph_out, out);
}

// Round 2
// 171.884 us; speedup vs baseline: 1.1198x; 1.1198x over previous
//
#include <hip/hip_runtime.h>

#define NN 2048     // nodes per graph
#define NG 64       // graphs
#define NE 16384    // edges per graph
#define BB 65536    // batch
#define META 64
#define TXD 8
#define NOISE 128

// ws layout:
//   [0, 32KB)      graph_out [64][128]
//   [32KB, 544KB)  emb       [64][2048]

// ---------------------------------------------------------------------------
// Kernel A: per-graph GCN aggregation -> emb[g][n]. One block per graph,
// deg/agg in LDS (deg = exact integer sum -> order-independent).
// ---------------------------------------------------------------------------
__global__ __launch_bounds__(256) void agg_kernel(
    const int* __restrict__ edges,     // [64,2,16384]
    const float* __restrict__ gcn_w,
    const float* __restrict__ gcn_b,
    float* __restrict__ emb)           // [64,2048] (ws)
{
    __shared__ float s_deg[NN];
    __shared__ float s_agg[NN];
    const int g = blockIdx.x, tid = threadIdx.x;
    const int* __restrict__ src = edges + (size_t)g * 2 * NE;
    const int* __restrict__ dst = src + NE;

    for (int n = tid; n < NN; n += 256) { s_deg[n] = 1.0f; s_agg[n] = 0.0f; }
    __syncthreads();
    for (int e = tid; e < NE; e += 256) atomicAdd(&s_deg[dst[e]], 1.0f);
    __syncthreads();
    for (int n = tid; n < NN; n += 256) s_deg[n] = rsqrtf(s_deg[n]);
    __syncthreads();
    for (int e = tid; e < NE; e += 256) {
        int s = src[e], d = dst[e];
        atomicAdd(&s_agg[d], s_deg[s] * s_deg[d]);
    }
    __syncthreads();
    const float w = gcn_w[0], b = gcn_b[0];
    for (int n = tid; n < NN; n += 256) {
        float di = s_deg[n];
        emb[(size_t)g * NN + n] = (s_agg[n] + di * di) * w + b;
    }
}

// ---------------------------------------------------------------------------
// Kernel B: fold emb @ emb_W[0:2048] -> graph_out[64][128].
// 1024 blocks = 64 graphs x 16 node-chunks of 128; atomicAdd into zeroed out.
// ---------------------------------------------------------------------------
__global__ __launch_bounds__(256) void fold_kernel(
    const float* __restrict__ emb,       // [64,2048]
    const float* __restrict__ emb_W,     // [2089,128]
    float* __restrict__ graph_out)       // [64,128], pre-zeroed
{
    __shared__ float s_e[128];
    const int tid = threadIdx.x;
    const int g = blockIdx.x >> 4, chunk = blockIdx.x & 15;
    const int n0 = chunk * 128;
    if (tid < 128) s_e[tid] = emb[(size_t)g * NN + n0 + tid];
    __syncthreads();
    const int c = tid & 127, h = tid >> 7;
    const float* __restrict__ Wp = emb_W + (size_t)(n0 + h * 64) * NOISE + c;
    const float* __restrict__ ep = s_e + h * 64;
    float a0 = 0.f, a1 = 0.f, a2 = 0.f, a3 = 0.f;
    #pragma unroll
    for (int i = 0; i < 64; i += 4) {
        a0 = fmaf(ep[i + 0], Wp[(i + 0) * NOISE], a0);
        a1 = fmaf(ep[i + 1], Wp[(i + 1) * NOISE], a1);
        a2 = fmaf(ep[i + 2], Wp[(i + 2) * NOISE], a2);
        a3 = fmaf(ep[i + 3], Wp[(i + 3) * NOISE], a3);
    }
    atomicAdd(&graph_out[g * NOISE + c], (a0 + a1) + (a2 + a3));
}

// ---------------------------------------------------------------------------
// Kernel C: main batched kernel. 32 rows per block, one shot, 2 barriers.
// trig_W transposed+padded in LDS (float4 reads); output weights in regs.
// ---------------------------------------------------------------------------
#define ROWS 32
__global__ __launch_bounds__(256) void main_kernel(
    const int* __restrict__ bg,          // [B]
    const float* __restrict__ chain,     // [B]
    const float* __restrict__ trig_in,   // [B,64]
    const float* __restrict__ txs,       // [B,8]
    const float* __restrict__ trig_W,    // [64,32]
    const float* __restrict__ trig_b,    // [32]
    const float* __restrict__ emb_W,     // [2089,128]
    const float* __restrict__ emb_b,     // [128]
    const float* __restrict__ graph_out, // [64,128]
    float* __restrict__ out)             // [B,128]
{
    __shared__ float s_twT[32 * 68];     // [j][i], pad 68 for b128 alignment
    __shared__ float s_tb[32];
    __shared__ float s_td[ROWS * META];  // 8 KB
    __shared__ float s_trig[ROWS * 32];  // 4 KB
    __shared__ float s_tx[ROWS * TXD];   // 1 KB
    __shared__ float s_chain[ROWS];
    __shared__ int   s_g[ROWS];

    const int tid = threadIdx.x;
    const int row0 = blockIdx.x * ROWS;

    // --- staging (one pass) ---
    for (int k = tid; k < META * 32; k += 256) {
        int i = k >> 5, j = k & 31;
        s_twT[j * 68 + i] = trig_W[k];
    }
    if (tid < 32) s_tb[tid] = trig_b[tid];
    for (int t = tid; t < ROWS * META / 4; t += 256)
        ((float4*)s_td)[t] = ((const float4*)(trig_in + (size_t)row0 * META))[t];
    if (tid < ROWS * TXD / 4)
        ((float4*)s_tx)[tid] = ((const float4*)(txs + (size_t)row0 * TXD))[tid];
    if (tid < ROWS) { s_chain[tid] = chain[row0 + tid]; s_g[tid] = bg[row0 + tid]; }

    // per-thread output-column weights (global loads overlap LDS staging)
    const int n = tid & 127;
    float w2[32], w3[TXD];
    #pragma unroll
    for (int j = 0; j < 32; ++j) w2[j] = emb_W[(size_t)(2049 + j) * NOISE + n];
    #pragma unroll
    for (int k = 0; k < TXD; ++k) w3[k] = emb_W[(size_t)(2081 + k) * NOISE + n];
    const float w1 = emb_W[(size_t)2048 * NOISE + n];
    const float bias = emb_b[n];

    __syncthreads();

    // --- phase 1: trig = relu(td @ trig_W + b), 4 rows per thread ---
    {
        const int j = tid & 31, r0 = tid >> 3 >> 2;  // tid>>5
        const float* __restrict__ twj = s_twT + j * 68;
        float acc[4];
        #pragma unroll
        for (int p = 0; p < 4; ++p) acc[p] = s_tb[j];
        #pragma unroll
        for (int i = 0; i < META; i += 4) {
            float4 tw = *(const float4*)(twj + i);
            #pragma unroll
            for (int p = 0; p < 4; ++p) {
                float4 t = *(const float4*)(s_td + (p * 8 + r0) * META + i);
                acc[p] = fmaf(t.x, tw.x, acc[p]);
                acc[p] = fmaf(t.y, tw.y, acc[p]);
                acc[p] = fmaf(t.z, tw.z, acc[p]);
                acc[p] = fmaf(t.w, tw.w, acc[p]);
            }
        }
        #pragma unroll
        for (int p = 0; p < 4; ++p)
            s_trig[(p * 8 + r0) * 32 + j] = fmaxf(acc[p], 0.f);
    }
    __syncthreads();

    // --- phase 2: one output column per thread, 16 rows each ---
    const int rb = tid >> 7;
    #pragma unroll
    for (int p = 0; p < 16; ++p) {
        const int r = p * 2 + rb;
        const int row = row0 + r;
        const int g = s_g[r];
        float acc = bias + graph_out[g * NOISE + n] + s_chain[r] * w1;
        const float4* __restrict__ tx4 = (const float4*)(s_tx + r * TXD);
        float4 t0 = tx4[0], t1 = tx4[1];
        acc = fmaf(t0.x, w3[0], acc); acc = fmaf(t0.y, w3[1], acc);
        acc = fmaf(t0.z, w3[2], acc); acc = fmaf(t0.w, w3[3], acc);
        acc = fmaf(t1.x, w3[4], acc); acc = fmaf(t1.y, w3[5], acc);
        acc = fmaf(t1.z, w3[6], acc); acc = fmaf(t1.w, w3[7], acc);
        const float4* __restrict__ tg4 = (const float4*)(s_trig + r * 32);
        #pragma unroll
        for (int q = 0; q < 8; ++q) {
            float4 t = tg4[q];
            acc = fmaf(t.x, w2[4 * q + 0], acc);
            acc = fmaf(t.y, w2[4 * q + 1], acc);
            acc = fmaf(t.z, w2[4 * q + 2], acc);
            acc = fmaf(t.w, w2[4 * q + 3], acc);
        }
        out[(size_t)row * NOISE + n] = acc;
    }
}

extern "C" void kernel_launch(void* const* d_in, const int* in_sizes, int n_in,
                              void* d_out, int out_size, void* d_ws, size_t ws_size,
                              hipStream_t stream) {
    const int*   bg      = (const int*)d_in[0];
    const float* chain   = (const float*)d_in[1];
    const float* trig_in = (const float*)d_in[2];
    const float* txs     = (const float*)d_in[3];
    const int*   edges   = (const int*)d_in[4];
    const float* gcn_w   = (const float*)d_in[5];
    const float* gcn_b   = (const float*)d_in[6];
    const float* trig_W  = (const float*)d_in[7];
    const float* trig_b  = (const float*)d_in[8];
    const float* emb_W   = (const float*)d_in[9];
    const float* emb_b   = (const float*)d_in[10];
    float* out = (float*)d_out;

    float* graph_out = (float*)d_ws;                 // 64*128 floats = 32 KB
    float* emb       = (float*)d_ws + NG * NOISE;    // 64*2048 floats = 512 KB

    hipMemsetAsync(graph_out, 0, NG * NOISE * sizeof(float), stream);
    agg_kernel<<<NG, 256, 0, stream>>>(edges, gcn_w, gcn_b, emb);
    fold_kernel<<<NG * 16, 256, 0, stream>>>(emb, emb_W, graph_out);
    main_kernel<<<BB / ROWS, 256, 0, stream>>>(bg, chain, trig_in, txs, trig_W,
                                               trig_b, emb_W, emb_b, graph_out, out);
}

// Round 3
// 171.323 us; speedup vs baseline: 1.1235x; 1.0033x over previous
//
#include <hip/hip_runtime.h>

#define NN 2048     // nodes per graph
#define NG 64       // graphs
#define NE 16384    // edges per graph
#define BB 65536    // batch
#define META 64
#define TXD 8
#define NOISE 128

// ws layout:
//   [0, 32KB)      graph_out [64][128]
//   [32KB, 544KB)  emb       [64][2048]

// ---------------------------------------------------------------------------
// Kernel A: per-graph GCN aggregation -> emb[g][n]. One block per graph.
// All 128 edge-visits per thread are register-batched int4 loads issued
// before the atomic phases: one latency exposure instead of 128.
// ---------------------------------------------------------------------------
__global__ __launch_bounds__(256) void agg_kernel(
    const int* __restrict__ edges,     // [64,2,16384]
    const float* __restrict__ gcn_w,
    const float* __restrict__ gcn_b,
    float* __restrict__ emb)           // [64,2048] (ws)
{
    __shared__ float s_deg[NN];
    __shared__ float s_agg[NN];
    const int g = blockIdx.x, tid = threadIdx.x;
    const int4* __restrict__ e4 = (const int4*)(edges + (size_t)g * 2 * NE);
    // src int4s at [0,4096), dst int4s at [4096,8192); 16 of each per thread.
    int4 ds[16], sr[16];
    #pragma unroll
    for (int k = 0; k < 16; ++k) ds[k] = e4[4096 + k * 256 + tid];
    #pragma unroll
    for (int k = 0; k < 16; ++k) sr[k] = e4[k * 256 + tid];

    for (int n = tid; n < NN; n += 256) { s_deg[n] = 1.0f; s_agg[n] = 0.0f; }
    __syncthreads();
    #pragma unroll
    for (int k = 0; k < 16; ++k) {
        atomicAdd(&s_deg[ds[k].x], 1.0f);
        atomicAdd(&s_deg[ds[k].y], 1.0f);
        atomicAdd(&s_deg[ds[k].z], 1.0f);
        atomicAdd(&s_deg[ds[k].w], 1.0f);
    }
    __syncthreads();
    for (int n = tid; n < NN; n += 256) s_deg[n] = rsqrtf(s_deg[n]);
    __syncthreads();
    #pragma unroll
    for (int k = 0; k < 16; ++k) {
        atomicAdd(&s_agg[ds[k].x], s_deg[sr[k].x] * s_deg[ds[k].x]);
        atomicAdd(&s_agg[ds[k].y], s_deg[sr[k].y] * s_deg[ds[k].y]);
        atomicAdd(&s_agg[ds[k].z], s_deg[sr[k].z] * s_deg[ds[k].z]);
        atomicAdd(&s_agg[ds[k].w], s_deg[sr[k].w] * s_deg[ds[k].w]);
    }
    __syncthreads();
    const float w = gcn_w[0], b = gcn_b[0];
    for (int n = tid; n < NN; n += 256) {
        float di = s_deg[n];
        emb[(size_t)g * NN + n] = (s_agg[n] + di * di) * w + b;
    }
}

// ---------------------------------------------------------------------------
// Kernel B: fold emb @ emb_W[0:2048] -> graph_out[64][128].
// 1024 blocks = 64 graphs x 16 node-chunks of 128; LDS-reduce then atomic.
// ---------------------------------------------------------------------------
__global__ __launch_bounds__(256) void fold_kernel(
    const float* __restrict__ emb,       // [64,2048]
    const float* __restrict__ emb_W,     // [2089,128]
    float* __restrict__ graph_out)       // [64,128], pre-zeroed
{
    __shared__ float s_e[128];
    __shared__ float s_red[128];
    const int tid = threadIdx.x;
    const int g = blockIdx.x >> 4, chunk = blockIdx.x & 15;
    const int n0 = chunk * 128;
    if (tid < 128) s_e[tid] = emb[(size_t)g * NN + n0 + tid];
    __syncthreads();
    const int c = tid & 127, h = tid >> 7;
    const float* __restrict__ Wp = emb_W + (size_t)(n0 + h * 64) * NOISE + c;
    const float* __restrict__ ep = s_e + h * 64;
    float a0 = 0.f, a1 = 0.f, a2 = 0.f, a3 = 0.f;
    #pragma unroll
    for (int i = 0; i < 64; i += 4) {
        a0 = fmaf(ep[i + 0], Wp[(i + 0) * NOISE], a0);
        a1 = fmaf(ep[i + 1], Wp[(i + 1) * NOISE], a1);
        a2 = fmaf(ep[i + 2], Wp[(i + 2) * NOISE], a2);
        a3 = fmaf(ep[i + 3], Wp[(i + 3) * NOISE], a3);
    }
    float acc = (a0 + a1) + (a2 + a3);
    if (h == 1) s_red[c] = acc;
    __syncthreads();
    if (h == 0) atomicAdd(&graph_out[g * NOISE + c], acc + s_red[c]);
}

// ---------------------------------------------------------------------------
// Kernel C: main batched kernel. 32 rows per block, one shot, 2 barriers.
// trig_W transposed+padded in LDS; output-column weights in registers;
// phase-2 row metadata + graph_out gathers hoisted out of the FMA loop.
// ---------------------------------------------------------------------------
#define ROWS 32
__global__ __launch_bounds__(256) void main_kernel(
    const int* __restrict__ bg,          // [B]
    const float* __restrict__ chain,     // [B]
    const float* __restrict__ trig_in,   // [B,64]
    const float* __restrict__ txs,       // [B,8]
    const float* __restrict__ trig_W,    // [64,32]
    const float* __restrict__ trig_b,    // [32]
    const float* __restrict__ emb_W,     // [2089,128]
    const float* __restrict__ emb_b,     // [128]
    const float* __restrict__ graph_out, // [64,128]
    float* __restrict__ out)             // [B,128]
{
    __shared__ float s_twT[32 * 68];     // [j][i], stride 68 (16B-aligned)
    __shared__ float s_tb[32];
    __shared__ float s_td[ROWS * META];  // 8 KB
    __shared__ float s_trig[ROWS * 32];  // 4 KB
    __shared__ float s_tx[ROWS * TXD];   // 1 KB
    __shared__ float s_chain[ROWS];
    __shared__ int   s_g[ROWS];

    const int tid = threadIdx.x;
    const int row0 = blockIdx.x * ROWS;

    // --- staging (one pass) ---
    for (int k = tid; k < META * 32; k += 256) {
        int i = k >> 5, j = k & 31;
        s_twT[j * 68 + i] = trig_W[k];
    }
    if (tid < 32) s_tb[tid] = trig_b[tid];
    for (int t = tid; t < ROWS * META / 4; t += 256)
        ((float4*)s_td)[t] = ((const float4*)(trig_in + (size_t)row0 * META))[t];
    if (tid < ROWS * TXD / 4)
        ((float4*)s_tx)[tid] = ((const float4*)(txs + (size_t)row0 * TXD))[tid];
    if (tid < ROWS) { s_chain[tid] = chain[row0 + tid]; s_g[tid] = bg[row0 + tid]; }

    // per-thread output-column weights (global loads overlap LDS staging)
    const int n = tid & 127;
    float w2[32], w3[TXD];
    #pragma unroll
    for (int j = 0; j < 32; ++j) w2[j] = emb_W[(size_t)(2049 + j) * NOISE + n];
    #pragma unroll
    for (int k = 0; k < TXD; ++k) w3[k] = emb_W[(size_t)(2081 + k) * NOISE + n];
    const float w1 = emb_W[(size_t)2048 * NOISE + n];
    const float bias = emb_b[n];

    __syncthreads();

    // --- phase 1: trig = relu(td @ trig_W + b), 4 rows per thread ---
    {
        const int j = tid & 31, r0 = tid >> 5;
        const float* __restrict__ twj = s_twT + j * 68;
        float acc[4];
        #pragma unroll
        for (int p = 0; p < 4; ++p) acc[p] = s_tb[j];
        #pragma unroll
        for (int i = 0; i < META; i += 4) {
            float4 tw = *(const float4*)(twj + i);
            #pragma unroll
            for (int p = 0; p < 4; ++p) {
                float4 t = *(const float4*)(s_td + (p * 8 + r0) * META + i);
                acc[p] = fmaf(t.x, tw.x, acc[p]);
                acc[p] = fmaf(t.y, tw.y, acc[p]);
                acc[p] = fmaf(t.z, tw.z, acc[p]);
                acc[p] = fmaf(t.w, tw.w, acc[p]);
            }
        }
        #pragma unroll
        for (int p = 0; p < 4; ++p)
            s_trig[(p * 8 + r0) * 32 + j] = fmaxf(acc[p], 0.f);
    }
    __syncthreads();

    // --- phase 2: one output column per thread, 16 rows each ---
    const int rb = tid >> 7;
    // hoist: row metadata + graph_out gathers (independent loads, one latency)
    float go[16], ch[16];
    #pragma unroll
    for (int p = 0; p < 16; ++p) {
        const int r = p * 2 + rb;
        const int g = s_g[r];
        ch[p] = s_chain[r];
        go[p] = graph_out[g * NOISE + n];
    }
    #pragma unroll
    for (int p = 0; p < 16; ++p) {
        const int r = p * 2 + rb;
        const int row = row0 + r;
        float acc = bias + go[p] + ch[p] * w1;
        const float4* __restrict__ tx4 = (const float4*)(s_tx + r * TXD);
        float4 t0 = tx4[0], t1 = tx4[1];
        acc = fmaf(t0.x, w3[0], acc); acc = fmaf(t0.y, w3[1], acc);
        acc = fmaf(t0.z, w3[2], acc); acc = fmaf(t0.w, w3[3], acc);
        acc = fmaf(t1.x, w3[4], acc); acc = fmaf(t1.y, w3[5], acc);
        acc = fmaf(t1.z, w3[6], acc); acc = fmaf(t1.w, w3[7], acc);
        const float4* __restrict__ tg4 = (const float4*)(s_trig + r * 32);
        #pragma unroll
        for (int q = 0; q < 8; ++q) {
            float4 t = tg4[q];
            acc = fmaf(t.x, w2[4 * q + 0], acc);
            acc = fmaf(t.y, w2[4 * q + 1], acc);
            acc = fmaf(t.z, w2[4 * q + 2], acc);
            acc = fmaf(t.w, w2[4 * q + 3], acc);
        }
        out[(size_t)row * NOISE + n] = acc;
    }
}

extern "C" void kernel_launch(void* const* d_in, const int* in_sizes, int n_in,
                              void* d_out, int out_size, void* d_ws, size_t ws_size,
                              hipStream_t stream) {
    const int*   bg      = (const int*)d_in[0];
    const float* chain   = (const float*)d_in[1];
    const float* trig_in = (const float*)d_in[2];
    const float* txs     = (const float*)d_in[3];
    const int*   edges   = (const int*)d_in[4];
    const float* gcn_w   = (const float*)d_in[5];
    const float* gcn_b   = (const float*)d_in[6];
    const float* trig_W  = (const float*)d_in[7];
    const float* trig_b  = (const float*)d_in[8];
    const float* emb_W   = (const float*)d_in[9];
    const float* emb_b   = (const float*)d_in[10];
    float* out = (float*)d_out;

    float* graph_out = (float*)d_ws;                 // 64*128 floats = 32 KB
    float* emb       = (float*)d_ws + NG * NOISE;    // 64*2048 floats = 512 KB

    hipMemsetAsync(graph_out, 0, NG * NOISE * sizeof(float), stream);
    agg_kernel<<<NG, 256, 0, stream>>>(edges, gcn_w, gcn_b, emb);
    fold_kernel<<<NG * 16, 256, 0, stream>>>(emb, emb_W, graph_out);
    main_kernel<<<BB / ROWS, 256, 0, stream>>>(bg, chain, trig_in, txs, trig_W,
                                               trig_b, emb_W, emb_b, graph_out, out);
}

// Round 4
// 132.635 us; speedup vs baseline: 1.4512x; 1.2917x over previous
//
#include <hip/hip_runtime.h>

#define NN 2048     // nodes per graph
#define NG 64       // graphs
#define NE 16384    // edges per graph
#define BB 65536    // batch
#define META 64
#define TXD 8
#define NOISE 128

// ws layout:
//   [0, 32KB)      graph_out [64][128]
//   [32KB, 544KB)  emb       [64][2048]

// ---------------------------------------------------------------------------
// Kernel A: per-graph GCN aggregation -> emb[g][n]. One block per graph.
// NO float LDS atomics (they lower to CAS loops): deg uses native int
// ds_add_u32; agg accumulates in u64 fixed-point (x 2^40) via ds_add_u64.
// Also zeroes graph_out[g][:] (fold adds atomically later in stream order).
// ---------------------------------------------------------------------------
__global__ __launch_bounds__(256) void agg_kernel(
    const int* __restrict__ edges,     // [64,2,16384]
    const float* __restrict__ gcn_w,
    const float* __restrict__ gcn_b,
    float* __restrict__ emb,           // [64,2048] (ws)
    float* __restrict__ graph_out)     // [64,128]  (ws, zeroed here)
{
    __shared__ int                s_cnt[NN];    // 8 KB
    __shared__ float              s_dinv[NN];   // 8 KB
    __shared__ unsigned long long s_acc[NN];    // 16 KB
    const int g = blockIdx.x, tid = threadIdx.x;
    const int4* __restrict__ e4 = (const int4*)(edges + (size_t)g * 2 * NE);

    if (tid < NOISE) graph_out[g * NOISE + tid] = 0.0f;

    // dst int4s live at [4096, 8192); batch into registers (64 VGPRs)
    int4 ds[16];
    #pragma unroll
    for (int k = 0; k < 16; ++k) ds[k] = e4[4096 + k * 256 + tid];

    for (int n = tid; n < NN; n += 256) { s_cnt[n] = 1; s_acc[n] = 0ull; }
    __syncthreads();

    #pragma unroll
    for (int k = 0; k < 16; ++k) {
        atomicAdd(&s_cnt[ds[k].x], 1);
        atomicAdd(&s_cnt[ds[k].y], 1);
        atomicAdd(&s_cnt[ds[k].z], 1);
        atomicAdd(&s_cnt[ds[k].w], 1);
    }
    __syncthreads();
    for (int n = tid; n < NN; n += 256) s_dinv[n] = rsqrtf((float)s_cnt[n]);
    __syncthreads();

    const float SCALE = 1099511627776.0f;  // 2^40
    #pragma unroll
    for (int k = 0; k < 16; ++k) {
        int4 sr = e4[k * 256 + tid];   // src int4s at [0, 4096)
        float nx = s_dinv[sr.x] * s_dinv[ds[k].x];
        float ny = s_dinv[sr.y] * s_dinv[ds[k].y];
        float nz = s_dinv[sr.z] * s_dinv[ds[k].z];
        float nw = s_dinv[sr.w] * s_dinv[ds[k].w];
        atomicAdd(&s_acc[ds[k].x], (unsigned long long)(nx * SCALE));
        atomicAdd(&s_acc[ds[k].y], (unsigned long long)(ny * SCALE));
        atomicAdd(&s_acc[ds[k].z], (unsigned long long)(nz * SCALE));
        atomicAdd(&s_acc[ds[k].w], (unsigned long long)(nw * SCALE));
    }
    __syncthreads();

    const float w = gcn_w[0], b = gcn_b[0];
    for (int n = tid; n < NN; n += 256) {
        float di = s_dinv[n];
        float agg = (float)((double)s_acc[n] * 0x1p-40) + di * di;
        emb[(size_t)g * NN + n] = agg * w + b;
    }
}

// ---------------------------------------------------------------------------
// Kernel B: fold emb @ emb_W[0:2048] -> graph_out[64][128].
// 1024 blocks = 64 graphs x 16 node-chunks of 128; LDS-reduce then atomic.
// ---------------------------------------------------------------------------
__global__ __launch_bounds__(256) void fold_kernel(
    const float* __restrict__ emb,       // [64,2048]
    const float* __restrict__ emb_W,     // [2089,128]
    float* __restrict__ graph_out)       // [64,128], zeroed by agg_kernel
{
    __shared__ float s_e[128];
    __shared__ float s_red[128];
    const int tid = threadIdx.x;
    const int g = blockIdx.x >> 4, chunk = blockIdx.x & 15;
    const int n0 = chunk * 128;
    if (tid < 128) s_e[tid] = emb[(size_t)g * NN + n0 + tid];
    __syncthreads();
    const int c = tid & 127, h = tid >> 7;
    const float* __restrict__ Wp = emb_W + (size_t)(n0 + h * 64) * NOISE + c;
    const float* __restrict__ ep = s_e + h * 64;
    float a0 = 0.f, a1 = 0.f, a2 = 0.f, a3 = 0.f;
    #pragma unroll
    for (int i = 0; i < 64; i += 4) {
        a0 = fmaf(ep[i + 0], Wp[(i + 0) * NOISE], a0);
        a1 = fmaf(ep[i + 1], Wp[(i + 1) * NOISE], a1);
        a2 = fmaf(ep[i + 2], Wp[(i + 2) * NOISE], a2);
        a3 = fmaf(ep[i + 3], Wp[(i + 3) * NOISE], a3);
    }
    float acc = (a0 + a1) + (a2 + a3);
    if (h == 1) s_red[c] = acc;
    __syncthreads();
    if (h == 0) atomicAdd(&graph_out[g * NOISE + c], acc + s_red[c]);
}

// ---------------------------------------------------------------------------
// Kernel C: main batched kernel. 32 rows per block, one shot, 2 barriers.
// trig_W transposed+padded in LDS; output-column weights in registers;
// phase-2 row metadata + graph_out gathers hoisted out of the FMA loop.
// ---------------------------------------------------------------------------
#define ROWS 32
__global__ __launch_bounds__(256) void main_kernel(
    const int* __restrict__ bg,          // [B]
    const float* __restrict__ chain,     // [B]
    const float* __restrict__ trig_in,   // [B,64]
    const float* __restrict__ txs,       // [B,8]
    const float* __restrict__ trig_W,    // [64,32]
    const float* __restrict__ trig_b,    // [32]
    const float* __restrict__ emb_W,     // [2089,128]
    const float* __restrict__ emb_b,     // [128]
    const float* __restrict__ graph_out, // [64,128]
    float* __restrict__ out)             // [B,128]
{
    __shared__ float s_twT[32 * 68];     // [j][i], stride 68 (16B-aligned)
    __shared__ float s_tb[32];
    __shared__ float s_td[ROWS * META];  // 8 KB
    __shared__ float s_trig[ROWS * 32];  // 4 KB
    __shared__ float s_tx[ROWS * TXD];   // 1 KB
    __shared__ float s_chain[ROWS];
    __shared__ int   s_g[ROWS];

    const int tid = threadIdx.x;
    const int row0 = blockIdx.x * ROWS;

    // --- staging (one pass) ---
    for (int k = tid; k < META * 32; k += 256) {
        int i = k >> 5, j = k & 31;
        s_twT[j * 68 + i] = trig_W[k];
    }
    if (tid < 32) s_tb[tid] = trig_b[tid];
    for (int t = tid; t < ROWS * META / 4; t += 256)
        ((float4*)s_td)[t] = ((const float4*)(trig_in + (size_t)row0 * META))[t];
    if (tid < ROWS * TXD / 4)
        ((float4*)s_tx)[tid] = ((const float4*)(txs + (size_t)row0 * TXD))[tid];
    if (tid < ROWS) { s_chain[tid] = chain[row0 + tid]; s_g[tid] = bg[row0 + tid]; }

    // per-thread output-column weights (global loads overlap LDS staging)
    const int n = tid & 127;
    float w2[32], w3[TXD];
    #pragma unroll
    for (int j = 0; j < 32; ++j) w2[j] = emb_W[(size_t)(2049 + j) * NOISE + n];
    #pragma unroll
    for (int k = 0; k < TXD; ++k) w3[k] = emb_W[(size_t)(2081 + k) * NOISE + n];
    const float w1 = emb_W[(size_t)2048 * NOISE + n];
    const float bias = emb_b[n];

    __syncthreads();

    // --- phase 1: trig = relu(td @ trig_W + b), 4 rows per thread ---
    {
        const int j = tid & 31, r0 = tid >> 5;
        const float* __restrict__ twj = s_twT + j * 68;
        float acc[4];
        #pragma unroll
        for (int p = 0; p < 4; ++p) acc[p] = s_tb[j];
        #pragma unroll
        for (int i = 0; i < META; i += 4) {
            float4 tw = *(const float4*)(twj + i);
            #pragma unroll
            for (int p = 0; p < 4; ++p) {
                float4 t = *(const float4*)(s_td + (p * 8 + r0) * META + i);
                acc[p] = fmaf(t.x, tw.x, acc[p]);
                acc[p] = fmaf(t.y, tw.y, acc[p]);
                acc[p] = fmaf(t.z, tw.z, acc[p]);
                acc[p] = fmaf(t.w, tw.w, acc[p]);
            }
        }
        #pragma unroll
        for (int p = 0; p < 4; ++p)
            s_trig[(p * 8 + r0) * 32 + j] = fmaxf(acc[p], 0.f);
    }
    __syncthreads();

    // --- phase 2: one output column per thread, 16 rows each ---
    const int rb = tid >> 7;
    float go[16], ch[16];
    #pragma unroll
    for (int p = 0; p < 16; ++p) {
        const int r = p * 2 + rb;
        const int g = s_g[r];
        ch[p] = s_chain[r];
        go[p] = graph_out[g * NOISE + n];
    }
    #pragma unroll
    for (int p = 0; p < 16; ++p) {
        const int r = p * 2 + rb;
        const int row = row0 + r;
        float acc = bias + go[p] + ch[p] * w1;
        const float4* __restrict__ tx4 = (const float4*)(s_tx + r * TXD);
        float4 t0 = tx4[0], t1 = tx4[1];
        acc = fmaf(t0.x, w3[0], acc); acc = fmaf(t0.y, w3[1], acc);
        acc = fmaf(t0.z, w3[2], acc); acc = fmaf(t0.w, w3[3], acc);
        acc = fmaf(t1.x, w3[4], acc); acc = fmaf(t1.y, w3[5], acc);
        acc = fmaf(t1.z, w3[6], acc); acc = fmaf(t1.w, w3[7], acc);
        const float4* __restrict__ tg4 = (const float4*)(s_trig + r * 32);
        #pragma unroll
        for (int q = 0; q < 8; ++q) {
            float4 t = tg4[q];
            acc = fmaf(t.x, w2[4 * q + 0], acc);
            acc = fmaf(t.y, w2[4 * q + 1], acc);
            acc = fmaf(t.z, w2[4 * q + 2], acc);
            acc = fmaf(t.w, w2[4 * q + 3], acc);
        }
        out[(size_t)row * NOISE + n] = acc;
    }
}

extern "C" void kernel_launch(void* const* d_in, const int* in_sizes, int n_in,
                              void* d_out, int out_size, void* d_ws, size_t ws_size,
                              hipStream_t stream) {
    const int*   bg      = (const int*)d_in[0];
    const float* chain   = (const float*)d_in[1];
    const float* trig_in = (const float*)d_in[2];
    const float* txs     = (const float*)d_in[3];
    const int*   edges   = (const int*)d_in[4];
    const float* gcn_w   = (const float*)d_in[5];
    const float* gcn_b   = (const float*)d_in[6];
    const float* trig_W  = (const float*)d_in[7];
    const float* trig_b  = (const float*)d_in[8];
    const float* emb_W   = (const float*)d_in[9];
    const float* emb_b   = (const float*)d_in[10];
    float* out = (float*)d_out;

    float* graph_out = (float*)d_ws;                 // 64*128 floats = 32 KB
    float* emb       = (float*)d_ws + NG * NOISE;    // 64*2048 floats = 512 KB

    agg_kernel<<<NG, 256, 0, stream>>>(edges, gcn_w, gcn_b, emb, graph_out);
    fold_kernel<<<NG * 16, 256, 0, stream>>>(emb, emb_W, graph_out);
    main_kernel<<<BB / ROWS, 256, 0, stream>>>(bg, chain, trig_in, txs, trig_W,
                                               trig_b, emb_W, emb_b, graph_out, out);
}

// Round 5
// 132.449 us; speedup vs baseline: 1.4532x; 1.0014x over previous
//
#include <hip/hip_runtime.h>

#define NN 2048     // nodes per graph
#define NG 64       // graphs
#define NE 16384    // edges per graph
#define BB 65536    // batch
#define META 64
#define TXD 8
#define NOISE 128

// ws layout:
//   [0, 32KB)      graph_out [64][128]
//   [32KB, 544KB)  emb       [64][2048]

// ---------------------------------------------------------------------------
// Kernel A: per-graph GCN aggregation -> emb[g][n]. One block per graph.
// Native int LDS atomics for deg; u64 fixed-point (x 2^40) for agg.
// Also zeroes graph_out[g][:] for fold's atomics.
// ---------------------------------------------------------------------------
__global__ __launch_bounds__(256) void agg_kernel(
    const int* __restrict__ edges,     // [64,2,16384]
    const float* __restrict__ gcn_w,
    const float* __restrict__ gcn_b,
    float* __restrict__ emb,           // [64,2048] (ws)
    float* __restrict__ graph_out)     // [64,128]  (ws, zeroed here)
{
    __shared__ int                s_cnt[NN];    // 8 KB
    __shared__ float              s_dinv[NN];   // 8 KB
    __shared__ unsigned long long s_acc[NN];    // 16 KB
    const int g = blockIdx.x, tid = threadIdx.x;
    const int4* __restrict__ e4 = (const int4*)(edges + (size_t)g * 2 * NE);

    if (tid < NOISE) graph_out[g * NOISE + tid] = 0.0f;

    int4 ds[16];
    #pragma unroll
    for (int k = 0; k < 16; ++k) ds[k] = e4[4096 + k * 256 + tid];

    for (int n = tid; n < NN; n += 256) { s_cnt[n] = 1; s_acc[n] = 0ull; }
    __syncthreads();

    #pragma unroll
    for (int k = 0; k < 16; ++k) {
        atomicAdd(&s_cnt[ds[k].x], 1);
        atomicAdd(&s_cnt[ds[k].y], 1);
        atomicAdd(&s_cnt[ds[k].z], 1);
        atomicAdd(&s_cnt[ds[k].w], 1);
    }
    __syncthreads();
    for (int n = tid; n < NN; n += 256) s_dinv[n] = rsqrtf((float)s_cnt[n]);
    __syncthreads();

    const float SCALE = 1099511627776.0f;  // 2^40
    #pragma unroll
    for (int k = 0; k < 16; ++k) {
        int4 sr = e4[k * 256 + tid];
        float nx = s_dinv[sr.x] * s_dinv[ds[k].x];
        float ny = s_dinv[sr.y] * s_dinv[ds[k].y];
        float nz = s_dinv[sr.z] * s_dinv[ds[k].z];
        float nw = s_dinv[sr.w] * s_dinv[ds[k].w];
        atomicAdd(&s_acc[ds[k].x], (unsigned long long)(nx * SCALE));
        atomicAdd(&s_acc[ds[k].y], (unsigned long long)(ny * SCALE));
        atomicAdd(&s_acc[ds[k].z], (unsigned long long)(nz * SCALE));
        atomicAdd(&s_acc[ds[k].w], (unsigned long long)(nw * SCALE));
    }
    __syncthreads();

    const float w = gcn_w[0], b = gcn_b[0];
    for (int n = tid; n < NN; n += 256) {
        float di = s_dinv[n];
        float agg = (float)((double)s_acc[n] * 0x1p-40) + di * di;
        emb[(size_t)g * NN + n] = agg * w + b;
    }
}

// ---------------------------------------------------------------------------
// Kernel B: fold emb @ emb_W[0:2048] -> graph_out[64][128].
// 1024 blocks = 64 graphs x 16 node-chunks of 128; LDS-reduce then atomic.
// ---------------------------------------------------------------------------
__global__ __launch_bounds__(256) void fold_kernel(
    const float* __restrict__ emb,       // [64,2048]
    const float* __restrict__ emb_W,     // [2089,128]
    float* __restrict__ graph_out)       // [64,128], zeroed by agg_kernel
{
    __shared__ float s_e[128];
    __shared__ float s_red[128];
    const int tid = threadIdx.x;
    const int g = blockIdx.x >> 4, chunk = blockIdx.x & 15;
    const int n0 = chunk * 128;
    if (tid < 128) s_e[tid] = emb[(size_t)g * NN + n0 + tid];
    __syncthreads();
    const int c = tid & 127, h = tid >> 7;
    const float* __restrict__ Wp = emb_W + (size_t)(n0 + h * 64) * NOISE + c;
    const float* __restrict__ ep = s_e + h * 64;
    float a0 = 0.f, a1 = 0.f, a2 = 0.f, a3 = 0.f;
    #pragma unroll
    for (int i = 0; i < 64; i += 4) {
        a0 = fmaf(ep[i + 0], Wp[(i + 0) * NOISE], a0);
        a1 = fmaf(ep[i + 1], Wp[(i + 1) * NOISE], a1);
        a2 = fmaf(ep[i + 2], Wp[(i + 2) * NOISE], a2);
        a3 = fmaf(ep[i + 3], Wp[(i + 3) * NOISE], a3);
    }
    float acc = (a0 + a1) + (a2 + a3);
    if (h == 1) s_red[c] = acc;
    __syncthreads();
    if (h == 0) atomicAdd(&graph_out[g * NOISE + c], acc + s_red[c]);
}

// ---------------------------------------------------------------------------
// Kernel C: main batched kernel. 32 rows/block, 2 barriers.
// Phase 1: (2j x 2r)/thread from bank-strided LDS. Phase 2: 2 cols/thread
// with w2/w3 in registers; tx/chain/bg read as wave-uniform scalar loads
// (no LDS); trig rows read as wave-uniform b128 broadcasts.
// ---------------------------------------------------------------------------
#define ROWS 32
__global__ __launch_bounds__(256, 3) void main_kernel(
    const int* __restrict__ bg,          // [B]
    const float* __restrict__ chain,     // [B]
    const float* __restrict__ trig_in,   // [B,64]
    const float* __restrict__ txs,       // [B,8]
    const float* __restrict__ trig_W,    // [64,32]
    const float* __restrict__ trig_b,    // [32]
    const float* __restrict__ emb_W,     // [2089,128]
    const float* __restrict__ emb_b,     // [128]
    const float* __restrict__ graph_out, // [64,128]
    float* __restrict__ out)             // [B,128]
{
    __shared__ float s_td[ROWS * 68];    // trigger rows, stride 68 (8.7 KB)
    __shared__ float s_twT[32 * 68];     // trig_W^T [j][i], stride 68 (8.7 KB)
    __shared__ float s_trig[ROWS * 36];  // relu'd trig, stride 36 (4.6 KB)

    const int tid = threadIdx.x;
    const int row0 = blockIdx.x * ROWS;

    // --- stage trigger rows: 32x64 floats = 512 float4 ---
    {
        const float4* __restrict__ gsrc =
            (const float4*)(trig_in + (size_t)row0 * META);
        #pragma unroll
        for (int k = 0; k < 2; ++k) {
            int t = tid + k * 256;
            int r = t >> 4, i4 = t & 15;
            *(float4*)&s_td[r * 68 + i4 * 4] = gsrc[t];
        }
    }
    // --- stage trig_W transposed: 512 float4, scatter ---
    {
        const float4* __restrict__ gsrc = (const float4*)trig_W;
        #pragma unroll
        for (int k = 0; k < 2; ++k) {
            int t = tid + k * 256;
            int i = t >> 3, j4 = (t & 7) * 4;
            float4 v = gsrc[t];
            s_twT[(j4 + 0) * 68 + i] = v.x;
            s_twT[(j4 + 1) * 68 + i] = v.y;
            s_twT[(j4 + 2) * 68 + i] = v.z;
            s_twT[(j4 + 3) * 68 + i] = v.w;
        }
    }

    // --- per-thread column-pair weights (overlap with staging latency) ---
    const int n0 = (tid & 63) * 2;
    float2 w2[32], w3[TXD];
    #pragma unroll
    for (int j = 0; j < 32; ++j)
        w2[j] = *(const float2*)&emb_W[(size_t)(2049 + j) * NOISE + n0];
    #pragma unroll
    for (int k = 0; k < TXD; ++k)
        w3[k] = *(const float2*)&emb_W[(size_t)(2081 + k) * NOISE + n0];
    const float2 w1   = *(const float2*)&emb_W[(size_t)2048 * NOISE + n0];
    const float2 bias = *(const float2*)&emb_b[n0];

    __syncthreads();

    // --- phase 1: trig = relu(td @ trig_W + b); (2 j, 2 rows) per thread ---
    {
        const int j0 = (tid & 15) * 2;
        const int r0 = (tid >> 4) * 2;
        const float* __restrict__ tw0 = s_twT + j0 * 68;
        const float* __restrict__ tw1 = s_twT + (j0 + 1) * 68;
        const float* __restrict__ td0 = s_td + r0 * 68;
        const float* __restrict__ td1 = s_td + (r0 + 1) * 68;
        float b0 = trig_b[j0], b1 = trig_b[j0 + 1];
        float a00 = b0, a01 = b1, a10 = b0, a11 = b1;
        #pragma unroll
        for (int i = 0; i < META; i += 4) {
            float4 u0 = *(const float4*)(tw0 + i);
            float4 u1 = *(const float4*)(tw1 + i);
            float4 t0 = *(const float4*)(td0 + i);
            float4 t1 = *(const float4*)(td1 + i);
            a00 = fmaf(t0.x, u0.x, a00); a00 = fmaf(t0.y, u0.y, a00);
            a00 = fmaf(t0.z, u0.z, a00); a00 = fmaf(t0.w, u0.w, a00);
            a01 = fmaf(t0.x, u1.x, a01); a01 = fmaf(t0.y, u1.y, a01);
            a01 = fmaf(t0.z, u1.z, a01); a01 = fmaf(t0.w, u1.w, a01);
            a10 = fmaf(t1.x, u0.x, a10); a10 = fmaf(t1.y, u0.y, a10);
            a10 = fmaf(t1.z, u0.z, a10); a10 = fmaf(t1.w, u0.w, a10);
            a11 = fmaf(t1.x, u1.x, a11); a11 = fmaf(t1.y, u1.y, a11);
            a11 = fmaf(t1.z, u1.z, a11); a11 = fmaf(t1.w, u1.w, a11);
        }
        s_trig[r0 * 36 + j0]           = fmaxf(a00, 0.f);
        s_trig[r0 * 36 + j0 + 1]       = fmaxf(a01, 0.f);
        s_trig[(r0 + 1) * 36 + j0]     = fmaxf(a10, 0.f);
        s_trig[(r0 + 1) * 36 + j0 + 1] = fmaxf(a11, 0.f);
    }
    __syncthreads();

    // --- phase 2: 8 rows x 2 cols per thread ---
    const int wv = tid >> 6;   // wave id -> row subset (wave-uniform rows)
    #pragma unroll
    for (int p = 0; p < 8; ++p) {
        const int r = p * 4 + wv;
        const int row = row0 + r;
        const int g = bg[row];                 // wave-uniform scalar load
        const float ch = chain[row];           // wave-uniform scalar load
        const float2 go2 = *(const float2*)&graph_out[g * NOISE + n0];
        float ax = bias.x + go2.x + ch * w1.x;
        float ay = bias.y + go2.y + ch * w1.y;
        #pragma unroll
        for (int k = 0; k < TXD; ++k) {
            float t = txs[(size_t)row * TXD + k];   // wave-uniform scalar load
            ax = fmaf(t, w3[k].x, ax);
            ay = fmaf(t, w3[k].y, ay);
        }
        const float* __restrict__ tg = s_trig + r * 36;
        #pragma unroll
        for (int q = 0; q < 8; ++q) {
            float4 t4 = *(const float4*)(tg + q * 4);   // broadcast b128
            ax = fmaf(t4.x, w2[4 * q + 0].x, ax); ay = fmaf(t4.x, w2[4 * q + 0].y, ay);
            ax = fmaf(t4.y, w2[4 * q + 1].x, ax); ay = fmaf(t4.y, w2[4 * q + 1].y, ay);
            ax = fmaf(t4.z, w2[4 * q + 2].x, ax); ay = fmaf(t4.z, w2[4 * q + 2].y, ay);
            ax = fmaf(t4.w, w2[4 * q + 3].x, ax); ay = fmaf(t4.w, w2[4 * q + 3].y, ay);
        }
        *(float2*)&out[(size_t)row * NOISE + n0] = make_float2(ax, ay);
    }
}

extern "C" void kernel_launch(void* const* d_in, const int* in_sizes, int n_in,
                              void* d_out, int out_size, void* d_ws, size_t ws_size,
                              hipStream_t stream) {
    const int*   bg      = (const int*)d_in[0];
    const float* chain   = (const float*)d_in[1];
    const float* trig_in = (const float*)d_in[2];
    const float* txs     = (const float*)d_in[3];
    const int*   edges   = (const int*)d_in[4];
    const float* gcn_w   = (const float*)d_in[5];
    const float* gcn_b   = (const float*)d_in[6];
    const float* trig_W  = (const float*)d_in[7];
    const float* trig_b  = (const float*)d_in[8];
    const float* emb_W   = (const float*)d_in[9];
    const float* emb_b   = (const float*)d_in[10];
    float* out = (float*)d_out;

    float* graph_out = (float*)d_ws;                 // 64*128 floats = 32 KB
    float* emb       = (float*)d_ws + NG * NOISE;    // 64*2048 floats = 512 KB

    agg_kernel<<<NG, 256, 0, stream>>>(edges, gcn_w, gcn_b, emb, graph_out);
    fold_kernel<<<NG * 16, 256, 0, stream>>>(emb, emb_W, graph_out);
    main_kernel<<<BB / ROWS, 256, 0, stream>>>(bg, chain, trig_in, txs, trig_W,
                                               trig_b, emb_W, emb_b, graph_out, out);
}

// Round 6
// 130.274 us; speedup vs baseline: 1.4775x; 1.0167x over previous
//
#include <hip/hip_runtime.h>

#define NN 2048     // nodes per graph
#define NG 64       // graphs
#define NE 16384    // edges per graph
#define BB 65536    // batch
#define META 64
#define TXD 8
#define NOISE 128

// ws layout:
//   [0, 32KB)      graph_out [64][128]
//   [32KB, 544KB)  emb       [64][2048]

// ---------------------------------------------------------------------------
// Kernel A: per-graph GCN aggregation -> emb[g][n]. One block per graph.
// Native int LDS atomics for deg; u64 fixed-point (x 2^40) for agg.
// Also zeroes graph_out[g][:] for fold's atomics.
// ---------------------------------------------------------------------------
__global__ __launch_bounds__(256) void agg_kernel(
    const int* __restrict__ edges,     // [64,2,16384]
    const float* __restrict__ gcn_w,
    const float* __restrict__ gcn_b,
    float* __restrict__ emb,           // [64,2048] (ws)
    float* __restrict__ graph_out)     // [64,128]  (ws, zeroed here)
{
    __shared__ int                s_cnt[NN];    // 8 KB
    __shared__ float              s_dinv[NN];   // 8 KB
    __shared__ unsigned long long s_acc[NN];    // 16 KB
    const int g = blockIdx.x, tid = threadIdx.x;
    const int4* __restrict__ e4 = (const int4*)(edges + (size_t)g * 2 * NE);

    if (tid < NOISE) graph_out[g * NOISE + tid] = 0.0f;

    int4 ds[16];
    #pragma unroll
    for (int k = 0; k < 16; ++k) ds[k] = e4[4096 + k * 256 + tid];

    for (int n = tid; n < NN; n += 256) { s_cnt[n] = 1; s_acc[n] = 0ull; }
    __syncthreads();

    #pragma unroll
    for (int k = 0; k < 16; ++k) {
        atomicAdd(&s_cnt[ds[k].x], 1);
        atomicAdd(&s_cnt[ds[k].y], 1);
        atomicAdd(&s_cnt[ds[k].z], 1);
        atomicAdd(&s_cnt[ds[k].w], 1);
    }
    __syncthreads();
    for (int n = tid; n < NN; n += 256) s_dinv[n] = rsqrtf((float)s_cnt[n]);
    __syncthreads();

    const float SCALE = 1099511627776.0f;  // 2^40
    #pragma unroll
    for (int k = 0; k < 16; ++k) {
        int4 sr = e4[k * 256 + tid];
        float nx = s_dinv[sr.x] * s_dinv[ds[k].x];
        float ny = s_dinv[sr.y] * s_dinv[ds[k].y];
        float nz = s_dinv[sr.z] * s_dinv[ds[k].z];
        float nw = s_dinv[sr.w] * s_dinv[ds[k].w];
        atomicAdd(&s_acc[ds[k].x], (unsigned long long)(nx * SCALE));
        atomicAdd(&s_acc[ds[k].y], (unsigned long long)(ny * SCALE));
        atomicAdd(&s_acc[ds[k].z], (unsigned long long)(nz * SCALE));
        atomicAdd(&s_acc[ds[k].w], (unsigned long long)(nw * SCALE));
    }
    __syncthreads();

    const float w = gcn_w[0], b = gcn_b[0];
    for (int n = tid; n < NN; n += 256) {
        float di = s_dinv[n];
        float agg = (float)((double)s_acc[n] * 0x1p-40) + di * di;
        emb[(size_t)g * NN + n] = agg * w + b;
    }
}

// ---------------------------------------------------------------------------
// Kernel B: fold emb @ emb_W[0:2048] -> graph_out[64][128].
// 1024 blocks = 64 graphs x 16 node-chunks of 128; LDS-reduce then atomic.
// ---------------------------------------------------------------------------
__global__ __launch_bounds__(256) void fold_kernel(
    const float* __restrict__ emb,       // [64,2048]
    const float* __restrict__ emb_W,     // [2089,128]
    float* __restrict__ graph_out)       // [64,128], zeroed by agg_kernel
{
    __shared__ float s_e[128];
    __shared__ float s_red[128];
    const int tid = threadIdx.x;
    const int g = blockIdx.x >> 4, chunk = blockIdx.x & 15;
    const int n0 = chunk * 128;
    if (tid < 128) s_e[tid] = emb[(size_t)g * NN + n0 + tid];
    __syncthreads();
    const int c = tid & 127, h = tid >> 7;
    const float* __restrict__ Wp = emb_W + (size_t)(n0 + h * 64) * NOISE + c;
    const float* __restrict__ ep = s_e + h * 64;
    float a0 = 0.f, a1 = 0.f, a2 = 0.f, a3 = 0.f;
    #pragma unroll
    for (int i = 0; i < 64; i += 4) {
        a0 = fmaf(ep[i + 0], Wp[(i + 0) * NOISE], a0);
        a1 = fmaf(ep[i + 1], Wp[(i + 1) * NOISE], a1);
        a2 = fmaf(ep[i + 2], Wp[(i + 2) * NOISE], a2);
        a3 = fmaf(ep[i + 3], Wp[(i + 3) * NOISE], a3);
    }
    float acc = (a0 + a1) + (a2 + a3);
    if (h == 1) s_red[c] = acc;
    __syncthreads();
    if (h == 0) atomicAdd(&graph_out[g * NOISE + c], acc + s_red[c]);
}

// ---------------------------------------------------------------------------
// Kernel C: main batched kernel. 32 rows/block, 2 barriers.
// Phase 1: (2 cols {j,j+16} x 2 rows)/thread, bank-spread LDS strides.
// Phase 2: 2 cols/thread, row metadata from LDS broadcasts, graph_out
// gathers hoisted/batched for MLP.
// ---------------------------------------------------------------------------
#define ROWS 32
__global__ __launch_bounds__(256, 3) void main_kernel(
    const int* __restrict__ bg,          // [B]
    const float* __restrict__ chain,     // [B]
    const float* __restrict__ trig_in,   // [B,64]
    const float* __restrict__ txs,       // [B,8]
    const float* __restrict__ trig_W,    // [64,32]
    const float* __restrict__ trig_b,    // [32]
    const float* __restrict__ emb_W,     // [2089,128]
    const float* __restrict__ emb_b,     // [128]
    const float* __restrict__ graph_out, // [64,128]
    float* __restrict__ out)             // [B,128]
{
    __shared__ float s_td[ROWS * 68];    // trigger rows, stride 68 (8.7 KB)
    __shared__ float s_twT[32 * 68];     // trig_W^T [j][i], stride 68 (8.7 KB)
    __shared__ float s_trig[ROWS * 36];  // relu'd trig, stride 36 (4.6 KB)
    __shared__ float s_tx[ROWS * TXD];   // 1 KB
    __shared__ float s_ch[ROWS];
    __shared__ int   s_gi[ROWS];

    const int tid = threadIdx.x;
    const int row0 = blockIdx.x * ROWS;

    // --- stage trigger rows: 32x64 floats = 512 float4 ---
    {
        const float4* __restrict__ gsrc =
            (const float4*)(trig_in + (size_t)row0 * META);
        #pragma unroll
        for (int k = 0; k < 2; ++k) {
            int t = tid + k * 256;
            int r = t >> 4, i4 = t & 15;
            *(float4*)&s_td[r * 68 + i4 * 4] = gsrc[t];
        }
    }
    // --- stage trig_W transposed: 512 float4, scatter ---
    {
        const float4* __restrict__ gsrc = (const float4*)trig_W;
        #pragma unroll
        for (int k = 0; k < 2; ++k) {
            int t = tid + k * 256;
            int i = t >> 3, j4 = (t & 7) * 4;
            float4 v = gsrc[t];
            s_twT[(j4 + 0) * 68 + i] = v.x;
            s_twT[(j4 + 1) * 68 + i] = v.y;
            s_twT[(j4 + 2) * 68 + i] = v.z;
            s_twT[(j4 + 3) * 68 + i] = v.w;
        }
    }
    // --- stage row metadata: tx (64 float4), chain, graph idx ---
    if (tid < 64) {
        int r = tid >> 1, k4 = (tid & 1) * 4;
        *(float4*)&s_tx[r * TXD + k4] =
            ((const float4*)(txs + (size_t)row0 * TXD))[tid];
    } else if (tid < 96) {
        int r = tid - 64;
        s_ch[r] = chain[row0 + r];
    } else if (tid < 128) {
        int r = tid - 96;
        s_gi[r] = bg[row0 + r];
    }

    // --- per-thread column-pair weights (overlap with staging latency) ---
    const int n0 = (tid & 63) * 2;
    float2 w2[32], w3[TXD];
    #pragma unroll
    for (int j = 0; j < 32; ++j)
        w2[j] = *(const float2*)&emb_W[(size_t)(2049 + j) * NOISE + n0];
    #pragma unroll
    for (int k = 0; k < TXD; ++k)
        w3[k] = *(const float2*)&emb_W[(size_t)(2081 + k) * NOISE + n0];
    const float2 w1   = *(const float2*)&emb_W[(size_t)2048 * NOISE + n0];
    const float2 bias = *(const float2*)&emb_b[n0];

    __syncthreads();

    // --- phase 1: trig = relu(td @ trig_W + b); cols {j0, j0+16} x 2 rows ---
    {
        const int j0 = tid & 15;            // bank-spread: 68*j0 covers all quads
        const int r0 = (tid >> 4) * 2;
        const float* __restrict__ tw0 = s_twT + j0 * 68;
        const float* __restrict__ tw1 = s_twT + (j0 + 16) * 68;
        const float* __restrict__ td0 = s_td + r0 * 68;
        const float* __restrict__ td1 = s_td + (r0 + 1) * 68;
        float b0 = trig_b[j0], b1 = trig_b[j0 + 16];
        float a00 = b0, a01 = b1, a10 = b0, a11 = b1;
        #pragma unroll
        for (int i = 0; i < META; i += 4) {
            float4 u0 = *(const float4*)(tw0 + i);
            float4 u1 = *(const float4*)(tw1 + i);
            float4 t0 = *(const float4*)(td0 + i);
            float4 t1 = *(const float4*)(td1 + i);
            a00 = fmaf(t0.x, u0.x, a00); a00 = fmaf(t0.y, u0.y, a00);
            a00 = fmaf(t0.z, u0.z, a00); a00 = fmaf(t0.w, u0.w, a00);
            a01 = fmaf(t0.x, u1.x, a01); a01 = fmaf(t0.y, u1.y, a01);
            a01 = fmaf(t0.z, u1.z, a01); a01 = fmaf(t0.w, u1.w, a01);
            a10 = fmaf(t1.x, u0.x, a10); a10 = fmaf(t1.y, u0.y, a10);
            a10 = fmaf(t1.z, u0.z, a10); a10 = fmaf(t1.w, u0.w, a10);
            a11 = fmaf(t1.x, u1.x, a11); a11 = fmaf(t1.y, u1.y, a11);
            a11 = fmaf(t1.z, u1.z, a11); a11 = fmaf(t1.w, u1.w, a11);
        }
        s_trig[r0 * 36 + j0]            = fmaxf(a00, 0.f);
        s_trig[r0 * 36 + j0 + 16]       = fmaxf(a01, 0.f);
        s_trig[(r0 + 1) * 36 + j0]      = fmaxf(a10, 0.f);
        s_trig[(r0 + 1) * 36 + j0 + 16] = fmaxf(a11, 0.f);
    }
    __syncthreads();

    // --- phase 2: 8 rows x 2 cols per thread ---
    const int wv = tid >> 6;   // rows wave-uniform -> LDS broadcasts
    // batch the graph_out gathers (independent -> one latency exposure)
    int   gs[8];
    float chs[8];
    #pragma unroll
    for (int p = 0; p < 8; ++p) {
        const int r = p * 4 + wv;
        gs[p]  = s_gi[r];
        chs[p] = s_ch[r];
    }
    float2 go[8];
    #pragma unroll
    for (int p = 0; p < 8; ++p)
        go[p] = *(const float2*)&graph_out[gs[p] * NOISE + n0];

    #pragma unroll
    for (int p = 0; p < 8; ++p) {
        const int r = p * 4 + wv;
        const int row = row0 + r;
        float ax = bias.x + go[p].x + chs[p] * w1.x;
        float ay = bias.y + go[p].y + chs[p] * w1.y;
        const float4* __restrict__ tx4 = (const float4*)(s_tx + r * TXD);
        float4 t0 = tx4[0], t1 = tx4[1];
        ax = fmaf(t0.x, w3[0].x, ax); ay = fmaf(t0.x, w3[0].y, ay);
        ax = fmaf(t0.y, w3[1].x, ax); ay = fmaf(t0.y, w3[1].y, ay);
        ax = fmaf(t0.z, w3[2].x, ax); ay = fmaf(t0.z, w3[2].y, ay);
        ax = fmaf(t0.w, w3[3].x, ax); ay = fmaf(t0.w, w3[3].y, ay);
        ax = fmaf(t1.x, w3[4].x, ax); ay = fmaf(t1.x, w3[4].y, ay);
        ax = fmaf(t1.y, w3[5].x, ax); ay = fmaf(t1.y, w3[5].y, ay);
        ax = fmaf(t1.z, w3[6].x, ax); ay = fmaf(t1.z, w3[6].y, ay);
        ax = fmaf(t1.w, w3[7].x, ax); ay = fmaf(t1.w, w3[7].y, ay);
        const float* __restrict__ tg = s_trig + r * 36;
        #pragma unroll
        for (int q = 0; q < 8; ++q) {
            float4 t4 = *(const float4*)(tg + q * 4);   // broadcast b128
            ax = fmaf(t4.x, w2[4 * q + 0].x, ax); ay = fmaf(t4.x, w2[4 * q + 0].y, ay);
            ax = fmaf(t4.y, w2[4 * q + 1].x, ax); ay = fmaf(t4.y, w2[4 * q + 1].y, ay);
            ax = fmaf(t4.z, w2[4 * q + 2].x, ax); ay = fmaf(t4.z, w2[4 * q + 2].y, ay);
            ax = fmaf(t4.w, w2[4 * q + 3].x, ax); ay = fmaf(t4.w, w2[4 * q + 3].y, ay);
        }
        *(float2*)&out[(size_t)row * NOISE + n0] = make_float2(ax, ay);
    }
}

extern "C" void kernel_launch(void* const* d_in, const int* in_sizes, int n_in,
                              void* d_out, int out_size, void* d_ws, size_t ws_size,
                              hipStream_t stream) {
    const int*   bg      = (const int*)d_in[0];
    const float* chain   = (const float*)d_in[1];
    const float* trig_in = (const float*)d_in[2];
    const float* txs     = (const float*)d_in[3];
    const int*   edges   = (const int*)d_in[4];
    const float* gcn_w   = (const float*)d_in[5];
    const float* gcn_b   = (const float*)d_in[6];
    const float* trig_W  = (const float*)d_in[7];
    const float* trig_b  = (const float*)d_in[8];
    const float* emb_W   = (const float*)d_in[9];
    const float* emb_b   = (const float*)d_in[10];
    float* out = (float*)d_out;

    float* graph_out = (float*)d_ws;                 // 64*128 floats = 32 KB
    float* emb       = (float*)d_ws + NG * NOISE;    // 64*2048 floats = 512 KB

    agg_kernel<<<NG, 256, 0, stream>>>(edges, gcn_w, gcn_b, emb, graph_out);
    fold_kernel<<<NG * 16, 256, 0, stream>>>(emb, emb_W, graph_out);
    main_kernel<<<BB / ROWS, 256, 0, stream>>>(bg, chain, trig_in, txs, trig_W,
                                               trig_b, emb_W, emb_b, graph_out, out);
}